// Round 4
// baseline (110.860 us; speedup 1.0000x reference)
//
#include <hip/hip_runtime.h>
#include <math.h>

#define EMBED   64
#define BATCH   2048
#define NTOT    4096
#define NITEMS  10000
#define TILE    64
#define NT      64               // NTOT/TILE
#define NTILES  2080             // NT*(NT+1)/2, == 8*260
#define SROW    66               // bf16 LDS row stride: 33 dwords == 1 mod 32

#define NB_NORM 625              // 625*16 = 10000 rows
#define B_BPP0  (1 + NB_NORM)    // 626
#define NB_BPP  128              // 128*16 = 2048 batch elems
#define GRID1   (B_BPP0 + NB_BPP)

typedef __attribute__((ext_vector_type(8))) short short8;
typedef __attribute__((ext_vector_type(4))) float f32x4;

__device__ __forceinline__ unsigned short f2bf(float f) {   // RNE fp32->bf16
    unsigned u = __float_as_uint(f);
    return (unsigned short)((u + 0x7FFFu + ((u >> 16) & 1u)) >> 16);
}

// block 0: counting sort of (id, orig) keys; block 1 also zeroes the tail
// counter; blocks 1..625: item norms; blocks 626..753: bpp softplus partials.
__global__ __launch_bounds__(1024) void combo_kernel(
    const int* __restrict__ user_id, const int* __restrict__ pos_id,
    const int* __restrict__ neg_id, const float* __restrict__ user_table,
    const float* __restrict__ item_table,
    int* __restrict__ sorted_id, int* __restrict__ sorted_orig,
    float* __restrict__ norms, float* __restrict__ bpp_part,
    int* __restrict__ counter)
{
    int blk = blockIdx.x, t = threadIdx.x;
    if (blk == 0) {
        __shared__ int hist[NITEMS];
        __shared__ unsigned key2[NTOT];
        __shared__ int wtot[16];
        for (int i = t; i < NITEMS; i += 1024) hist[i] = 0;
        __syncthreads();
        for (int i = t; i < NTOT; i += 1024) {
            int id = (i < BATCH) ? pos_id[i] : neg_id[i - BATCH];
            atomicAdd(&hist[id], 1);
        }
        __syncthreads();
        // exclusive scan over 10000 bins: 10 bins/thread, wave-shfl scan
        int b0 = t * 10, bend = min(b0 + 10, NITEMS);
        int s = 0;
        for (int b = b0; b < bend; ++b) s += hist[b];
        int lane = t & 63, wid = t >> 6;
        int v = s;
        #pragma unroll
        for (int off = 1; off < 64; off <<= 1) {
            int y = __shfl_up(v, off, 64);
            if (lane >= off) v += y;
        }
        if (lane == 63) wtot[wid] = v;
        __syncthreads();
        if (t == 0) {
            int run = 0;
            #pragma unroll
            for (int w = 0; w < 16; ++w) { int c = wtot[w]; wtot[w] = run; run += c; }
        }
        __syncthreads();
        int running = v - s + wtot[wid];   // exclusive prefix for this thread's bins
        for (int b = b0; b < bend; ++b) { int c = hist[b]; hist[b] = running; running += c; }
        __syncthreads();
        // scatter (atomic within bin), canonicalize equal-id runs by orig pos
        for (int i = t; i < NTOT; i += 1024) {
            int id = (i < BATCH) ? pos_id[i] : neg_id[i - BATCH];
            int pos = atomicAdd(&hist[id], 1);
            key2[pos] = ((unsigned)id << 12) | (unsigned)i;
        }
        __syncthreads();
        for (int p = 0; p < 12; ++p) {          // odd-even; run length <=12 whp
            int start = p & 1;
            for (int q = t; q < NTOT / 2; q += 1024) {
                int a = 2 * q + start;
                if (a + 1 < NTOT) {
                    unsigned x = key2[a], y = key2[a + 1];
                    if (x > y) { key2[a] = y; key2[a + 1] = x; }
                }
            }
            __syncthreads();
        }
        for (int i = t; i < NTOT; i += 1024) {
            sorted_id[i]   = (int)(key2[i] >> 12);
            sorted_orig[i] = (int)(key2[i] & 4095u);
        }
    } else if (blk < B_BPP0) {
        if (blk == 1 && t == 0) *counter = 0;   // reset tail counter (replay-safe)
        int row  = (blk - 1) * 16 + (t >> 6);
        int lane = t & 63;
        float v = item_table[row * EMBED + lane];
        float sft = v * v;
        #pragma unroll
        for (int off = 32; off; off >>= 1) sft += __shfl_xor(sft, off, 64);
        if (lane == 0) norms[row] = sft;
    } else {
        int b    = (blk - B_BPP0) * 16 + (t >> 6);
        int lane = t & 63;
        float u = user_table[user_id[b] * EMBED + lane];
        float p = item_table[pos_id[b]  * EMBED + lane];
        float n = item_table[neg_id[b]  * EMBED + lane];
        float dp = u * p, dn = u * n;
        #pragma unroll
        for (int off = 32; off; off >>= 1) {
            dp += __shfl_xor(dp, off, 64);
            dn += __shfl_xor(dn, off, 64);
        }
        float x = dn - dp;
        float sp = fmaxf(x, 0.f) + log1pf(expf(-fabsf(x)));
        __shared__ float red[16];
        if (lane == 0) red[t >> 6] = sp;
        __syncthreads();
        if (t == 0) {
            float ssum = 0.f;
            #pragma unroll
            for (int w = 0; w < 16; ++w) ssum += red[w];
            bpp_part[blk - B_BPP0] = ssum;
        }
    }
}

// One block per upper-tri 64x64 tile: MFMA dot tile + masked D-gather.
// Last-finishing block performs the final deterministic reduction.
__global__ __launch_bounds__(256) void reg_kernel(
    const float* __restrict__ item_table,
    const int* __restrict__ sorted_id, const int* __restrict__ sorted_orig,
    const float* __restrict__ norms, const float* __restrict__ D,
    float* __restrict__ partials, const float* __restrict__ bpp_part,
    int* __restrict__ counter, float* __restrict__ out)
{
    __shared__ unsigned short sa[TILE][SROW];
    __shared__ unsigned short sb[TILE][SROW];
    __shared__ float sqi[TILE], sqj[TILE];
    __shared__ int idi[TILE], idj[TILE], idiN[TILE], idjN[TILE], ogi[TILE], ogj[TILE];
    __shared__ float wsum[4];
    __shared__ int lastFlag;
    __shared__ float fred[256];

    // XCD-aware swizzle: 2080 = 8 * 260 exactly -> bijective
    int bs = blockIdx.x;
    int b  = (bs & 7) * (NTILES / 8) + (bs >> 3);
    int tI = 0, rem = b;
    while (rem >= NT - tI) { rem -= NT - tI; ++tI; }
    int tJ = tI + rem;

    int t = threadIdx.x;
    int r = t >> 2, c = t & 3;    // staging: row 0..63, 16-float chunk 0..3

    if (t < TILE) {
        int g = tI * TILE + t, id = sorted_id[g];
        sqi[t] = norms[id]; idi[t] = id; idiN[t] = id * NITEMS; ogi[t] = sorted_orig[g];
    } else if (t < 2 * TILE) {
        int rr = t - TILE, g = tJ * TILE + rr, id = sorted_id[g];
        sqj[rr] = norms[id]; idj[rr] = id; idjN[rr] = id * NITEMS; ogj[rr] = sorted_orig[g];
    }

    {   // stage both 64x64 fp32 slabs from item_table, convert to bf16
        int idI = sorted_id[tI * TILE + r];
        int idJ = sorted_id[tJ * TILE + r];
        const float4* srcI = (const float4*)&item_table[idI * EMBED + c * 16];
        const float4* srcJ = (const float4*)&item_table[idJ * EMBED + c * 16];
        float4 aI[4], aJ[4];
        #pragma unroll
        for (int k = 0; k < 4; ++k) { aI[k] = srcI[k]; aJ[k] = srcJ[k]; }
        short8 vI0, vI1, vJ0, vJ1;
        #pragma unroll
        for (int k = 0; k < 2; ++k) {
            vI0[4*k+0] = (short)f2bf(aI[k].x);  vI0[4*k+1] = (short)f2bf(aI[k].y);
            vI0[4*k+2] = (short)f2bf(aI[k].z);  vI0[4*k+3] = (short)f2bf(aI[k].w);
            vJ0[4*k+0] = (short)f2bf(aJ[k].x);  vJ0[4*k+1] = (short)f2bf(aJ[k].y);
            vJ0[4*k+2] = (short)f2bf(aJ[k].z);  vJ0[4*k+3] = (short)f2bf(aJ[k].w);
            vI1[4*k+0] = (short)f2bf(aI[k+2].x); vI1[4*k+1] = (short)f2bf(aI[k+2].y);
            vI1[4*k+2] = (short)f2bf(aI[k+2].z); vI1[4*k+3] = (short)f2bf(aI[k+2].w);
            vJ1[4*k+0] = (short)f2bf(aJ[k+2].x); vJ1[4*k+1] = (short)f2bf(aJ[k+2].y);
            vJ1[4*k+2] = (short)f2bf(aJ[k+2].z); vJ1[4*k+3] = (short)f2bf(aJ[k+2].w);
        }
        *(short8*)&sa[r][c * 16]     = vI0;
        *(short8*)&sa[r][c * 16 + 8] = vI1;
        *(short8*)&sb[r][c * 16]     = vJ0;
        *(short8*)&sb[r][c * 16 + 8] = vJ1;
    }
    __syncthreads();

    // MFMA: wave w owns rows [w*16, w*16+16) x all 64 cols; K=64 in 2 steps.
    int w = t >> 6, l = t & 63;
    int arow = w * 16 + (l & 15);
    int kb   = (l >> 4) * 8;
    f32x4 acc[4];
    #pragma unroll
    for (int cb = 0; cb < 4; ++cb) acc[cb] = (f32x4){0.f, 0.f, 0.f, 0.f};
    #pragma unroll
    for (int s = 0; s < 2; ++s) {
        short8 af = *(const short8*)&sa[arow][s * 32 + kb];
        #pragma unroll
        for (int cb = 0; cb < 4; ++cb) {
            short8 bf = *(const short8*)&sb[cb * 16 + (l & 15)][s * 32 + kb];
            acc[cb] = __builtin_amdgcn_mfma_f32_16x16x32_bf16(af, bf, acc[cb], 0, 0, 0);
        }
    }

    // epilogue: C/D map col=lane&15, row=(lane>>4)*4+reg (m89-verified)
    float accsum = 0.f;
    #pragma unroll
    for (int cb = 0; cb < 4; ++cb) {
        #pragma unroll
        for (int rr = 0; rr < 4; ++rr) {
            int i_loc = w * 16 + (l >> 4) * 4 + rr;
            int j_loc = cb * 16 + (l & 15);
            int gi = tI * TILE + i_loc, gj = tJ * TILE + j_loc;
            float d2 = sqi[i_loc] + sqj[j_loc] - 2.f * acc[cb][rr];
            if (gi < gj && d2 > 0.f) {
                bool fwd = ogi[i_loc] < ogj[j_loc];
                int addr = fwd ? (idiN[i_loc] + idj[j_loc]) : (idjN[j_loc] + idi[i_loc]);
                accsum += D[addr] * sqrtf(d2);
            }
        }
    }

    // wave shfl-reduce, then block sum via 4-entry LDS
    #pragma unroll
    for (int off = 32; off; off >>= 1) accsum += __shfl_xor(accsum, off, 64);
    if (l == 0) wsum[w] = accsum;
    __syncthreads();
    if (t == 0) {
        partials[b] = wsum[0] + wsum[1] + wsum[2] + wsum[3];
        __threadfence();
        int old = atomicAdd(counter, 1);
        lastFlag = (old == NTILES - 1);
    }
    __syncthreads();
    if (lastFlag) {
        __threadfence();   // acquire: invalidate stale L2 before reading partials
        float s1 = 0.f, s2 = 0.f;
        for (int i = t; i < NB_BPP; i += 256) s1 += bpp_part[i];
        for (int i = t; i < NTILES; i += 256) s2 += partials[i];
        fred[t] = s2;
        __syncthreads();
        #pragma unroll
        for (int s = 128; s; s >>= 1) {
            if (t < s) fred[t] += fred[t + s];
            __syncthreads();
        }
        float s2tot = fred[0];
        __syncthreads();
        fred[t] = s1;
        __syncthreads();
        #pragma unroll
        for (int s = 128; s; s >>= 1) {
            if (t < s) fred[t] += fred[t + s];
            __syncthreads();
        }
        if (t == 0) { out[0] = fred[0]; out[1] = s2tot; }
    }
}

extern "C" void kernel_launch(void* const* d_in, const int* in_sizes, int n_in,
                              void* d_out, int out_size, void* d_ws, size_t ws_size,
                              hipStream_t stream) {
    const int*   user_id    = (const int*)  d_in[0];
    const int*   pos_id     = (const int*)  d_in[1];
    const int*   neg_id     = (const int*)  d_in[2];
    const float* user_table = (const float*)d_in[3];
    const float* item_table = (const float*)d_in[4];
    const float* D          = (const float*)d_in[5];
    float* out = (float*)d_out;

    int*   sorted_id   = (int*)d_ws;                    // 4096
    int*   sorted_orig = sorted_id + NTOT;              // 4096
    float* norms       = (float*)(sorted_orig + NTOT);  // 10000
    float* bpp_part    = norms + NITEMS;                // 128
    float* reg_part    = bpp_part + NB_BPP;             // 2080
    int*   counter     = (int*)(reg_part + NTILES);     // 1

    combo_kernel<<<GRID1, 1024, 0, stream>>>(user_id, pos_id, neg_id, user_table,
                                             item_table, sorted_id, sorted_orig,
                                             norms, bpp_part, counter);
    reg_kernel<<<NTILES, 256, 0, stream>>>(item_table, sorted_id, sorted_orig,
                                           norms, D, reg_part, bpp_part, counter, out);
}

// Round 5
// 49.937 us; speedup vs baseline: 2.2200x; 2.2200x over previous
//
#include <hip/hip_runtime.h>
#include <math.h>

#define EMBED   64
#define BATCH   2048
#define NTOT    4096
#define NITEMS  10000
#define TILE    64
#define NT      64               // NTOT/TILE
#define NTILES  2080             // NT*(NT+1)/2, == 8*260
#define SROW    66               // bf16 LDS row stride: 33 dwords == 1 mod 32

#define NB_NORM 625              // 625*16 = 10000 rows
#define B_BPP0  (1 + NB_NORM)    // 626
#define NB_BPP  128              // 128*16 = 2048 batch elems
#define GRID1   (B_BPP0 + NB_BPP)

typedef __attribute__((ext_vector_type(8))) short short8;
typedef __attribute__((ext_vector_type(4))) float f32x4;

__device__ __forceinline__ unsigned short f2bf(float f) {   // RNE fp32->bf16
    unsigned u = __float_as_uint(f);
    return (unsigned short)((u + 0x7FFFu + ((u >> 16) & 1u)) >> 16);
}

// block 0: counting sort of (id, orig) keys; blocks 1..625: item norms;
// blocks 626..753: bpp softplus partials. All independent -> run concurrently.
__global__ __launch_bounds__(1024) void combo_kernel(
    const int* __restrict__ user_id, const int* __restrict__ pos_id,
    const int* __restrict__ neg_id, const float* __restrict__ user_table,
    const float* __restrict__ item_table,
    int* __restrict__ sorted_id, int* __restrict__ sorted_orig,
    float* __restrict__ norms, float* __restrict__ bpp_part)
{
    int blk = blockIdx.x, t = threadIdx.x;
    if (blk == 0) {
        __shared__ int hist[NITEMS];
        __shared__ unsigned key2[NTOT];
        __shared__ int wtot[16];
        for (int i = t; i < NITEMS; i += 1024) hist[i] = 0;
        __syncthreads();
        for (int i = t; i < NTOT; i += 1024) {
            int id = (i < BATCH) ? pos_id[i] : neg_id[i - BATCH];
            atomicAdd(&hist[id], 1);
        }
        __syncthreads();
        // exclusive scan over 10000 bins: 10 bins/thread, wave-shfl scan
        int b0 = t * 10, bend = min(b0 + 10, NITEMS);
        int s = 0;
        for (int b = b0; b < bend; ++b) s += hist[b];
        int lane = t & 63, wid = t >> 6;
        int v = s;
        #pragma unroll
        for (int off = 1; off < 64; off <<= 1) {
            int y = __shfl_up(v, off, 64);
            if (lane >= off) v += y;
        }
        if (lane == 63) wtot[wid] = v;
        __syncthreads();
        if (t == 0) {
            int run = 0;
            #pragma unroll
            for (int w = 0; w < 16; ++w) { int c = wtot[w]; wtot[w] = run; run += c; }
        }
        __syncthreads();
        int running = v - s + wtot[wid];   // exclusive prefix for this thread's bins
        for (int b = b0; b < bend; ++b) { int c = hist[b]; hist[b] = running; running += c; }
        __syncthreads();
        // scatter (atomic within bin), canonicalize equal-id runs by orig pos
        for (int i = t; i < NTOT; i += 1024) {
            int id = (i < BATCH) ? pos_id[i] : neg_id[i - BATCH];
            int pos = atomicAdd(&hist[id], 1);
            key2[pos] = ((unsigned)id << 12) | (unsigned)i;
        }
        __syncthreads();
        for (int p = 0; p < 12; ++p) {          // odd-even; run length <=12 whp
            int start = p & 1;
            for (int q = t; q < NTOT / 2; q += 1024) {
                int a = 2 * q + start;
                if (a + 1 < NTOT) {
                    unsigned x = key2[a], y = key2[a + 1];
                    if (x > y) { key2[a] = y; key2[a + 1] = x; }
                }
            }
            __syncthreads();
        }
        for (int i = t; i < NTOT; i += 1024) {
            sorted_id[i]   = (int)(key2[i] >> 12);
            sorted_orig[i] = (int)(key2[i] & 4095u);
        }
    } else if (blk < B_BPP0) {
        int row  = (blk - 1) * 16 + (t >> 6);
        int lane = t & 63;
        float v = item_table[row * EMBED + lane];
        float sft = v * v;
        #pragma unroll
        for (int off = 32; off; off >>= 1) sft += __shfl_xor(sft, off, 64);
        if (lane == 0) norms[row] = sft;
    } else {
        int b    = (blk - B_BPP0) * 16 + (t >> 6);
        int lane = t & 63;
        float u = user_table[user_id[b] * EMBED + lane];
        float p = item_table[pos_id[b]  * EMBED + lane];
        float n = item_table[neg_id[b]  * EMBED + lane];
        float dp = u * p, dn = u * n;
        #pragma unroll
        for (int off = 32; off; off >>= 1) {
            dp += __shfl_xor(dp, off, 64);
            dn += __shfl_xor(dn, off, 64);
        }
        float x = dn - dp;
        float sp = fmaxf(x, 0.f) + log1pf(expf(-fabsf(x)));
        __shared__ float red[16];
        if (lane == 0) red[t >> 6] = sp;
        __syncthreads();
        if (t == 0) {
            float ssum = 0.f;
            #pragma unroll
            for (int w = 0; w < 16; ++w) ssum += red[w];
            bpp_part[blk - B_BPP0] = ssum;
        }
    }
}

// One block per upper-tri 64x64 tile: MFMA dot tile + masked D-gather.
__global__ __launch_bounds__(256) void reg_kernel(
    const float* __restrict__ item_table,
    const int* __restrict__ sorted_id, const int* __restrict__ sorted_orig,
    const float* __restrict__ norms, const float* __restrict__ D,
    float* __restrict__ partials)
{
    __shared__ unsigned short sa[TILE][SROW];
    __shared__ unsigned short sb[TILE][SROW];
    __shared__ float sqi[TILE], sqj[TILE];
    __shared__ int idi[TILE], idj[TILE], idiN[TILE], idjN[TILE], ogi[TILE], ogj[TILE];
    __shared__ float wsum[4];

    // XCD-aware swizzle: 2080 = 8 * 260 exactly -> bijective
    int bs = blockIdx.x;
    int b  = (bs & 7) * (NTILES / 8) + (bs >> 3);
    int tI = 0, rem = b;
    while (rem >= NT - tI) { rem -= NT - tI; ++tI; }
    int tJ = tI + rem;

    int t = threadIdx.x;
    int r = t >> 2, c = t & 3;    // staging: row 0..63, 16-float chunk 0..3

    if (t < TILE) {
        int g = tI * TILE + t, id = sorted_id[g];
        sqi[t] = norms[id]; idi[t] = id; idiN[t] = id * NITEMS; ogi[t] = sorted_orig[g];
    } else if (t < 2 * TILE) {
        int rr = t - TILE, g = tJ * TILE + rr, id = sorted_id[g];
        sqj[rr] = norms[id]; idj[rr] = id; idjN[rr] = id * NITEMS; ogj[rr] = sorted_orig[g];
    }

    {   // stage both 64x64 fp32 slabs from item_table, convert to bf16
        int idI = sorted_id[tI * TILE + r];
        int idJ = sorted_id[tJ * TILE + r];
        const float4* srcI = (const float4*)&item_table[idI * EMBED + c * 16];
        const float4* srcJ = (const float4*)&item_table[idJ * EMBED + c * 16];
        float4 aI[4], aJ[4];
        #pragma unroll
        for (int k = 0; k < 4; ++k) { aI[k] = srcI[k]; aJ[k] = srcJ[k]; }
        short8 vI0, vI1, vJ0, vJ1;
        #pragma unroll
        for (int k = 0; k < 2; ++k) {
            vI0[4*k+0] = (short)f2bf(aI[k].x);  vI0[4*k+1] = (short)f2bf(aI[k].y);
            vI0[4*k+2] = (short)f2bf(aI[k].z);  vI0[4*k+3] = (short)f2bf(aI[k].w);
            vJ0[4*k+0] = (short)f2bf(aJ[k].x);  vJ0[4*k+1] = (short)f2bf(aJ[k].y);
            vJ0[4*k+2] = (short)f2bf(aJ[k].z);  vJ0[4*k+3] = (short)f2bf(aJ[k].w);
            vI1[4*k+0] = (short)f2bf(aI[k+2].x); vI1[4*k+1] = (short)f2bf(aI[k+2].y);
            vI1[4*k+2] = (short)f2bf(aI[k+2].z); vI1[4*k+3] = (short)f2bf(aI[k+2].w);
            vJ1[4*k+0] = (short)f2bf(aJ[k+2].x); vJ1[4*k+1] = (short)f2bf(aJ[k+2].y);
            vJ1[4*k+2] = (short)f2bf(aJ[k+2].z); vJ1[4*k+3] = (short)f2bf(aJ[k+2].w);
        }
        *(short8*)&sa[r][c * 16]     = vI0;
        *(short8*)&sa[r][c * 16 + 8] = vI1;
        *(short8*)&sb[r][c * 16]     = vJ0;
        *(short8*)&sb[r][c * 16 + 8] = vJ1;
    }
    __syncthreads();

    // MFMA: wave w owns rows [w*16, w*16+16) x all 64 cols; K=64 in 2 steps.
    int w = t >> 6, l = t & 63;
    int arow = w * 16 + (l & 15);
    int kb   = (l >> 4) * 8;
    f32x4 acc[4];
    #pragma unroll
    for (int cb = 0; cb < 4; ++cb) acc[cb] = (f32x4){0.f, 0.f, 0.f, 0.f};
    #pragma unroll
    for (int s = 0; s < 2; ++s) {
        short8 af = *(const short8*)&sa[arow][s * 32 + kb];
        #pragma unroll
        for (int cb = 0; cb < 4; ++cb) {
            short8 bf = *(const short8*)&sb[cb * 16 + (l & 15)][s * 32 + kb];
            acc[cb] = __builtin_amdgcn_mfma_f32_16x16x32_bf16(af, bf, acc[cb], 0, 0, 0);
        }
    }

    // epilogue: C/D map col=lane&15, row=(lane>>4)*4+reg (m89-verified).
    // Branchless; gi<gj check only needed on diagonal tiles (wave-uniform).
    float accsum = 0.f;
    int i_base = w * 16 + (l >> 4) * 4;
    int j_loc  = 0;
    if (tI != tJ) {
        #pragma unroll
        for (int cb = 0; cb < 4; ++cb) {
            j_loc = cb * 16 + (l & 15);
            float sqb = sqj[j_loc];
            int   idb = idj[j_loc], idbN = idjN[j_loc], ob = ogj[j_loc];
            #pragma unroll
            for (int rr = 0; rr < 4; ++rr) {
                int i_loc = i_base + rr;
                float d2 = sqi[i_loc] + sqb - 2.f * acc[cb][rr];
                bool fwd = ogi[i_loc] < ob;
                int addr = fwd ? (idiN[i_loc] + idb) : (idbN + idi[i_loc]);
                float dg = D[addr];
                accsum = (d2 > 0.f) ? fmaf(dg, sqrtf(d2), accsum) : accsum;
            }
        }
    } else {
        #pragma unroll
        for (int cb = 0; cb < 4; ++cb) {
            j_loc = cb * 16 + (l & 15);
            float sqb = sqj[j_loc];
            int   idb = idj[j_loc], idbN = idjN[j_loc], ob = ogj[j_loc];
            #pragma unroll
            for (int rr = 0; rr < 4; ++rr) {
                int i_loc = i_base + rr;
                float d2 = sqi[i_loc] + sqb - 2.f * acc[cb][rr];
                bool fwd = ogi[i_loc] < ob;
                int addr = fwd ? (idiN[i_loc] + idb) : (idbN + idi[i_loc]);
                float dg = D[addr];
                bool m = (i_loc < j_loc) && (d2 > 0.f);
                accsum = m ? fmaf(dg, sqrtf(d2), accsum) : accsum;
            }
        }
    }

    // wave shfl-reduce, then block sum via 4-entry LDS
    #pragma unroll
    for (int off = 32; off; off >>= 1) accsum += __shfl_xor(accsum, off, 64);
    if (l == 0) wsum[w] = accsum;
    __syncthreads();
    if (t == 0) partials[b] = wsum[0] + wsum[1] + wsum[2] + wsum[3];
}

__global__ __launch_bounds__(256) void reduce_kernel(const float* __restrict__ bpp_part,
                                                     const float* __restrict__ reg_part,
                                                     float* __restrict__ out) {
    int t = threadIdx.x;
    float s1 = 0.f, s2 = 0.f;
    for (int i = t; i < NB_BPP; i += 256) s1 += bpp_part[i];
    for (int i = t; i < NTILES; i += 256) s2 += reg_part[i];
    __shared__ float r1[256], r2[256];
    r1[t] = s1; r2[t] = s2;
    __syncthreads();
    #pragma unroll
    for (int s = 128; s; s >>= 1) {
        if (t < s) { r1[t] += r1[t + s]; r2[t] += r2[t + s]; }
        __syncthreads();
    }
    if (t == 0) { out[0] = r1[0]; out[1] = r2[0]; }
}

extern "C" void kernel_launch(void* const* d_in, const int* in_sizes, int n_in,
                              void* d_out, int out_size, void* d_ws, size_t ws_size,
                              hipStream_t stream) {
    const int*   user_id    = (const int*)  d_in[0];
    const int*   pos_id     = (const int*)  d_in[1];
    const int*   neg_id     = (const int*)  d_in[2];
    const float* user_table = (const float*)d_in[3];
    const float* item_table = (const float*)d_in[4];
    const float* D          = (const float*)d_in[5];
    float* out = (float*)d_out;

    int*   sorted_id   = (int*)d_ws;                    // 4096
    int*   sorted_orig = sorted_id + NTOT;              // 4096
    float* norms       = (float*)(sorted_orig + NTOT);  // 10000
    float* bpp_part    = norms + NITEMS;                // 128
    float* reg_part    = bpp_part + NB_BPP;             // 2080

    combo_kernel<<<GRID1, 1024, 0, stream>>>(user_id, pos_id, neg_id, user_table,
                                             item_table, sorted_id, sorted_orig,
                                             norms, bpp_part);
    reg_kernel<<<NTILES, 256, 0, stream>>>(item_table, sorted_id, sorted_orig,
                                           norms, D, reg_part);
    reduce_kernel<<<1, 256, 0, stream>>>(bpp_part, reg_part, out);
}

// Round 6
// 41.849 us; speedup vs baseline: 2.6490x; 1.1932x over previous
//
#include <hip/hip_runtime.h>
#include <math.h>

#define EMBED   64
#define BATCH   2048
#define NTOT    4096
#define NITEMS  10000
#define TILE    64
#define NT      64               // NTOT/TILE
#define NTILES  2080             // NT*(NT+1)/2, == 8*260
#define SROW    66               // bf16 LDS row stride: 33 dwords == 1 mod 32

#define NB_NORM 625              // 625*16 = 10000 rows
#define B_BPP0  (1 + NB_NORM)    // 626
#define NB_BPP  128              // 128*16 = 2048 batch elems
#define GRID1   (B_BPP0 + NB_BPP)

typedef __attribute__((ext_vector_type(8))) short short8;
typedef __attribute__((ext_vector_type(4))) float f32x4;

__device__ __forceinline__ unsigned short f2bf(float f) {   // RNE fp32->bf16
    unsigned u = __float_as_uint(f);
    return (unsigned short)((u + 0x7FFFu + ((u >> 16) & 1u)) >> 16);
}

// block 0: counting sort of (id, orig) keys; blocks 1..625: item norms;
// blocks 626..753: bpp softplus partials. All independent -> run concurrently.
__global__ __launch_bounds__(1024) void combo_kernel(
    const int* __restrict__ user_id, const int* __restrict__ pos_id,
    const int* __restrict__ neg_id, const float* __restrict__ user_table,
    const float* __restrict__ item_table,
    int* __restrict__ sorted_id, int* __restrict__ sorted_orig,
    float* __restrict__ norms, float* __restrict__ bpp_part)
{
    int blk = blockIdx.x, t = threadIdx.x;
    if (blk == 0) {
        __shared__ int hist[NITEMS];
        __shared__ unsigned key2[NTOT];
        __shared__ int wtot[16];
        for (int i = t; i < NITEMS; i += 1024) hist[i] = 0;
        __syncthreads();
        for (int i = t; i < NTOT; i += 1024) {
            int id = (i < BATCH) ? pos_id[i] : neg_id[i - BATCH];
            atomicAdd(&hist[id], 1);
        }
        __syncthreads();
        // exclusive scan over 10000 bins: 10 bins/thread, wave-shfl scan
        int b0 = t * 10, bend = min(b0 + 10, NITEMS);
        int s = 0;
        for (int b = b0; b < bend; ++b) s += hist[b];
        int lane = t & 63, wid = t >> 6;
        int v = s;
        #pragma unroll
        for (int off = 1; off < 64; off <<= 1) {
            int y = __shfl_up(v, off, 64);
            if (lane >= off) v += y;
        }
        if (lane == 63) wtot[wid] = v;
        __syncthreads();
        if (t == 0) {
            int run = 0;
            #pragma unroll
            for (int w = 0; w < 16; ++w) { int c = wtot[w]; wtot[w] = run; run += c; }
        }
        __syncthreads();
        int running = v - s + wtot[wid];   // exclusive prefix for this thread's bins
        for (int b = b0; b < bend; ++b) { int c = hist[b]; hist[b] = running; running += c; }
        __syncthreads();
        // scatter (atomic within bin), canonicalize equal-id runs by orig pos
        for (int i = t; i < NTOT; i += 1024) {
            int id = (i < BATCH) ? pos_id[i] : neg_id[i - BATCH];
            int pos = atomicAdd(&hist[id], 1);
            key2[pos] = ((unsigned)id << 12) | (unsigned)i;
        }
        __syncthreads();
        for (int p = 0; p < 12; ++p) {          // odd-even; run length <=12 whp
            int start = p & 1;
            for (int q = t; q < NTOT / 2; q += 1024) {
                int a = 2 * q + start;
                if (a + 1 < NTOT) {
                    unsigned x = key2[a], y = key2[a + 1];
                    if (x > y) { key2[a] = y; key2[a + 1] = x; }
                }
            }
            __syncthreads();
        }
        for (int i = t; i < NTOT; i += 1024) {
            sorted_id[i]   = (int)(key2[i] >> 12);
            sorted_orig[i] = (int)(key2[i] & 4095u);
        }
    } else if (blk < B_BPP0) {
        int row  = (blk - 1) * 16 + (t >> 6);
        int lane = t & 63;
        float v = item_table[row * EMBED + lane];
        float sft = v * v;
        #pragma unroll
        for (int off = 32; off; off >>= 1) sft += __shfl_xor(sft, off, 64);
        if (lane == 0) norms[row] = sft;
    } else {
        int b    = (blk - B_BPP0) * 16 + (t >> 6);
        int lane = t & 63;
        float u = user_table[user_id[b] * EMBED + lane];
        float p = item_table[pos_id[b]  * EMBED + lane];
        float n = item_table[neg_id[b]  * EMBED + lane];
        float dp = u * p, dn = u * n;
        #pragma unroll
        for (int off = 32; off; off >>= 1) {
            dp += __shfl_xor(dp, off, 64);
            dn += __shfl_xor(dn, off, 64);
        }
        float x = dn - dp;
        float sp = fmaxf(x, 0.f) + log1pf(expf(-fabsf(x)));
        __shared__ float red[16];
        if (lane == 0) red[t >> 6] = sp;
        __syncthreads();
        if (t == 0) {
            float ssum = 0.f;
            #pragma unroll
            for (int w = 0; w < 16; ++w) ssum += red[w];
            bpp_part[blk - B_BPP0] = ssum;
        }
    }
}

// One block per upper-tri 64x64 tile: MFMA dot tile + masked D-gather.
// Gathers are issued BEFORE the MFMA section so L3 latency hides under it.
__global__ __launch_bounds__(256) void reg_kernel(
    const float* __restrict__ item_table,
    const int* __restrict__ sorted_id, const int* __restrict__ sorted_orig,
    const float* __restrict__ norms, const float* __restrict__ D,
    float* __restrict__ partials)
{
    __shared__ unsigned short sa[TILE][SROW];
    __shared__ unsigned short sb[TILE][SROW];
    __shared__ float sqi[TILE], sqj[TILE];
    __shared__ int idi[TILE], idj[TILE], idiN[TILE], idjN[TILE], ogi[TILE], ogj[TILE];
    __shared__ float wsum[4];

    // XCD-aware swizzle: 2080 = 8 * 260 exactly -> bijective
    int bs = blockIdx.x;
    int b  = (bs & 7) * (NTILES / 8) + (bs >> 3);
    int tI = 0, rem = b;
    while (rem >= NT - tI) { rem -= NT - tI; ++tI; }
    int tJ = tI + rem;

    int t = threadIdx.x;
    int r = t >> 2, c = t & 3;    // staging: row 0..63, 16-float chunk 0..3

    if (t < TILE) {
        int g = tI * TILE + t, id = sorted_id[g];
        sqi[t] = norms[id]; idi[t] = id; idiN[t] = id * NITEMS; ogi[t] = sorted_orig[g];
    } else if (t < 2 * TILE) {
        int rr = t - TILE, g = tJ * TILE + rr, id = sorted_id[g];
        sqj[rr] = norms[id]; idj[rr] = id; idjN[rr] = id * NITEMS; ogj[rr] = sorted_orig[g];
    }

    {   // stage both 64x64 fp32 slabs from item_table, convert to bf16
        int idI = sorted_id[tI * TILE + r];
        int idJ = sorted_id[tJ * TILE + r];
        const float4* srcI = (const float4*)&item_table[idI * EMBED + c * 16];
        const float4* srcJ = (const float4*)&item_table[idJ * EMBED + c * 16];
        #pragma unroll
        for (int k = 0; k < 4; ++k) {
            float4 aI = srcI[k];
            float4 aJ = srcJ[k];
            ushort4 sI = { f2bf(aI.x), f2bf(aI.y), f2bf(aI.z), f2bf(aI.w) };
            ushort4 sJ = { f2bf(aJ.x), f2bf(aJ.y), f2bf(aJ.z), f2bf(aJ.w) };
            *(ushort4*)&sa[r][c * 16 + k * 4] = sI;
            *(ushort4*)&sb[r][c * 16 + k * 4] = sJ;
        }
    }
    __syncthreads();

    int w = t >> 6, l = t & 63;
    int i_base = w * 16 + (l >> 4) * 4;

    // Phase 1: compute all 16 gather addresses (independent of MFMA) and
    // issue the loads up-front — one latency window, hidden under MFMA.
    int addr[16];
    #pragma unroll
    for (int cb = 0; cb < 4; ++cb) {
        int j_loc = cb * 16 + (l & 15);
        int idb = idj[j_loc], idbN = idjN[j_loc], ob = ogj[j_loc];
        #pragma unroll
        for (int rr = 0; rr < 4; ++rr) {
            int i_loc = i_base + rr;
            bool fwd = ogi[i_loc] < ob;
            addr[cb * 4 + rr] = fwd ? (idiN[i_loc] + idb) : (idbN + idi[i_loc]);
        }
    }
    float dg[16];
    #pragma unroll
    for (int k = 0; k < 16; ++k) dg[k] = D[addr[k]];

    // Phase 2: MFMA dot tile. Wave w owns rows [w*16,w*16+16) x 64 cols.
    int arow = w * 16 + (l & 15);
    int kb   = (l >> 4) * 8;
    f32x4 acc[4];
    #pragma unroll
    for (int cb = 0; cb < 4; ++cb) acc[cb] = (f32x4){0.f, 0.f, 0.f, 0.f};
    #pragma unroll
    for (int s = 0; s < 2; ++s) {
        short8 af = *(const short8*)&sa[arow][s * 32 + kb];
        #pragma unroll
        for (int cb = 0; cb < 4; ++cb) {
            short8 bf = *(const short8*)&sb[cb * 16 + (l & 15)][s * 32 + kb];
            acc[cb] = __builtin_amdgcn_mfma_f32_16x16x32_bf16(af, bf, acc[cb], 0, 0, 0);
        }
    }

    // Phase 3: distances, mask, fma with gathered D.
    // C/D map col=lane&15, row=(lane>>4)*4+reg (m89-verified).
    bool offdiag = (tI != tJ);   // wave-uniform
    float accsum = 0.f;
    #pragma unroll
    for (int cb = 0; cb < 4; ++cb) {
        int j_loc = cb * 16 + (l & 15);
        float sqb = sqj[j_loc];
        #pragma unroll
        for (int rr = 0; rr < 4; ++rr) {
            int i_loc = i_base + rr;
            float d2 = sqi[i_loc] + sqb - 2.f * acc[cb][rr];
            bool m = (d2 > 0.f) && (offdiag || (i_loc < j_loc));
            accsum = m ? fmaf(dg[cb * 4 + rr], sqrtf(d2), accsum) : accsum;
        }
    }

    // wave shfl-reduce, then block sum via 4-entry LDS
    #pragma unroll
    for (int off = 32; off; off >>= 1) accsum += __shfl_xor(accsum, off, 64);
    if (l == 0) wsum[w] = accsum;
    __syncthreads();
    if (t == 0) partials[b] = wsum[0] + wsum[1] + wsum[2] + wsum[3];
}

__global__ __launch_bounds__(256) void reduce_kernel(const float* __restrict__ bpp_part,
                                                     const float* __restrict__ reg_part,
                                                     float* __restrict__ out) {
    int t = threadIdx.x;
    float s1 = 0.f, s2 = 0.f;
    for (int i = t; i < NB_BPP; i += 256) s1 += bpp_part[i];
    for (int i = t; i < NTILES; i += 256) s2 += reg_part[i];
    __shared__ float r1[256], r2[256];
    r1[t] = s1; r2[t] = s2;
    __syncthreads();
    #pragma unroll
    for (int s = 128; s; s >>= 1) {
        if (t < s) { r1[t] += r1[t + s]; r2[t] += r2[t + s]; }
        __syncthreads();
    }
    if (t == 0) { out[0] = r1[0]; out[1] = r2[0]; }
}

extern "C" void kernel_launch(void* const* d_in, const int* in_sizes, int n_in,
                              void* d_out, int out_size, void* d_ws, size_t ws_size,
                              hipStream_t stream) {
    const int*   user_id    = (const int*)  d_in[0];
    const int*   pos_id     = (const int*)  d_in[1];
    const int*   neg_id     = (const int*)  d_in[2];
    const float* user_table = (const float*)d_in[3];
    const float* item_table = (const float*)d_in[4];
    const float* D          = (const float*)d_in[5];
    float* out = (float*)d_out;

    int*   sorted_id   = (int*)d_ws;                    // 4096
    int*   sorted_orig = sorted_id + NTOT;              // 4096
    float* norms       = (float*)(sorted_orig + NTOT);  // 10000
    float* bpp_part    = norms + NITEMS;                // 128
    float* reg_part    = bpp_part + NB_BPP;             // 2080

    combo_kernel<<<GRID1, 1024, 0, stream>>>(user_id, pos_id, neg_id, user_table,
                                             item_table, sorted_id, sorted_orig,
                                             norms, bpp_part);
    reg_kernel<<<NTILES, 256, 0, stream>>>(item_table, sorted_id, sorted_orig,
                                           norms, D, reg_part);
    reduce_kernel<<<1, 256, 0, stream>>>(bpp_part, reg_part, out);
}